// Round 20
// baseline (100.801 us; speedup 1.0000x reference)
//
#include <hip/hip_runtime.h>
#include <stdint.h>

#define NB_ 8
#define NC_ 128
#define NN_ 4096

typedef float f32x4 __attribute__((ext_vector_type(4)));
typedef _Float16 f16x8 __attribute__((ext_vector_type(8)));
typedef short s16x8 __attribute__((ext_vector_type(8)));
typedef unsigned short u16x4 __attribute__((ext_vector_type(4)));

__device__ __forceinline__ uint16_t f2bf(float f) {
    union { float f; uint32_t u; } v; v.f = f;
    return (uint16_t)((v.u + 0x7FFFu + ((v.u >> 16) & 1u)) >> 16);
}
__device__ __forceinline__ float bf2f(uint16_t b) {
    union { uint32_t u; float f; } v; v.u = ((uint32_t)b) << 16;
    return v.f;
}

// ---- prep: xt = fp16 x^T [N][C] (Q loads) + fragment-ordered Kf / Vf ----
// Kf chunk (tile t, ms, cc): lane l holds x^T[t*32+ms*16+(l&15)][cc*32+(l>>4)*8+j]
//   fp16 x8, at Kf[((t*8+ms*4+cc)*64+l)*8]  (k=32 QK A/B layout).
// Vf chunk (tile t, cs): lane l, slot j holds x[cs*16+(l&15)][t*32 + dualmap]
//   where dualmap(g,j) = (j<4) ? g*4+j : 16+g*4+(j-4)  -- matches the slot map
//   of the in-register P (both ms-halves) -> zero-shuffle k=32 PV.
__global__ __launch_bounds__(256) void prep_kernel(
        const float* __restrict__ pts, _Float16* __restrict__ xt,
        _Float16* __restrict__ Kf, uint16_t* __restrict__ Vf) {
    __shared__ float T[64][65];
    int bid = blockIdx.x;
    int ct = bid & 1, nt = (bid >> 1) & 63, b = bid >> 7;
    int c0 = ct * 64, n0 = nt * 64;
    int lr = threadIdx.x >> 6, lc = threadIdx.x & 63;
    const float* src = pts + ((size_t)b * NC_ + c0) * NN_ + n0;
#pragma unroll
    for (int r = 0; r < 16; ++r) {
        int cl = r * 4 + lr;
        T[cl][lc] = src[(size_t)cl * NN_ + lc];
    }
    __syncthreads();
#pragma unroll
    for (int r = 0; r < 16; ++r) {
        int nl = r * 4 + lr;
        xt[((size_t)b * NN_ + n0 + nl) * NC_ + c0 + lc] = (_Float16)T[lc][nl];
    }

    int w = threadIdx.x >> 6, l = threadIdx.x & 63, l15 = l & 15, g = l >> 4;
    _Float16* Kfb = Kf + (size_t)b * 524288;
    uint16_t* Vfb = Vf + (size_t)b * 524288;
#pragma unroll
    for (int e = 0; e < 2; ++e) {
        int q2 = w + e * 4;
        int tl = q2 >> 2, msq = (q2 >> 1) & 1, ccl = q2 & 1;
        int t = nt * 2 + tl, cc = ct * 2 + ccl;
        f16x8 kv;
#pragma unroll
        for (int j = 0; j < 8; ++j)
            kv[j] = (_Float16)T[ccl * 32 + g * 8 + j][tl * 32 + msq * 16 + l15];
        *(f16x8*)(Kfb + (((size_t)t * 8 + msq * 4 + cc) * 64 + l) * 8) = kv;
    }
#pragma unroll
    for (int e = 0; e < 2; ++e) {
        int q2 = w + e * 4;
        int tl = q2 >> 2, csl = q2 & 3;
        int t = nt * 2 + tl, cs = ct * 4 + csl;
        s16x8 vv;
#pragma unroll
        for (int j = 0; j < 8; ++j) {
            int m = (j < 4) ? (g * 4 + j) : (16 + g * 4 + (j - 4));
            vv[j] = (short)f2bf(T[csl * 16 + l15][tl * 32 + m]);
        }
        *(s16x8*)(Vfb + (((size_t)t * 8 + cs) * 64 + l) * 8) = vv;
    }
}

// ---------------- flash: fused QK^T -> exp -> PV, fixed shift 64 ----------
// R19 skeleton (T4 counted vmcnt(4), raw s_barrier, triple-buffered K/V,
// fragment-linear gll staging) + VALU diet:
//  - lsum via ones-row MFMA (accl): removes 16 adds/iter + end shuffles,
//    l consistent with the bf16 P used by PV.
//  - bf16-trunc pack via v_perm_b32 (1 inst/pair; sel in SGPR).
//  - exp path = fmaf + exp2f (2 insts/value guaranteed).
// Zero-shuffle P (swapped QK + dualmap k=32 PV). Partials self-normalized.
template <int MSPLIT>
__global__ __launch_bounds__(256, 3) void flash_kernel(
        const _Float16* __restrict__ xt, const _Float16* __restrict__ Kf,
        const uint16_t* __restrict__ Vf,
        uint16_t* __restrict__ Opart, float* __restrict__ lpart,
        const float* __restrict__ pts, const float* __restrict__ gamma,
        float* __restrict__ out) {
    int bid = blockIdx.x;
    int b = bid & 7;
    int rest = bid >> 3;
    int nb = rest & 31;
    int mh = rest >> 5;          // 0..MSPLIT-1
    int tid = threadIdx.x;
    int w = tid >> 6, l = tid & 63, l15 = l & 15, g = l >> 4;

    // 3 buffers x (8KB K + 8KB V), fragment-linear
    __shared__ __align__(16) uint16_t KV[3 * 8192];

    int nbase = nb * 128 + w * 32;
    const _Float16* xtb = xt + (size_t)b * NN_ * NC_;
    const char* KfB = (const char*)(Kf + (size_t)b * 524288);
    const char* VfB = (const char*)(Vf + (size_t)b * 524288);
    char* KVB = (char*)KV;
    int so = tid * 16;           // thread's 16B slot (linear staging)

    // 4 gll loads per STAGE (K 2 halves + V 2 halves)
#define STAGE(TILE, BUFOFF) do {                                                       \
        size_t gb_ = (size_t)(TILE) * 8192 + so;                                       \
        int lb_ = (BUFOFF) + so;                                                       \
        __builtin_amdgcn_global_load_lds(                                              \
            (const __attribute__((address_space(1))) void*)(KfB + gb_),                \
            (__attribute__((address_space(3))) void*)(KVB + lb_), 16, 0, 0);           \
        __builtin_amdgcn_global_load_lds(                                              \
            (const __attribute__((address_space(1))) void*)(KfB + gb_ + 4096),         \
            (__attribute__((address_space(3))) void*)(KVB + lb_ + 4096), 16, 0, 0);    \
        __builtin_amdgcn_global_load_lds(                                              \
            (const __attribute__((address_space(1))) void*)(VfB + gb_),                \
            (__attribute__((address_space(3))) void*)(KVB + lb_ + 8192), 16, 0, 0);    \
        __builtin_amdgcn_global_load_lds(                                              \
            (const __attribute__((address_space(1))) void*)(VfB + gb_ + 4096),         \
            (__attribute__((address_space(3))) void*)(KVB + lb_ + 12288), 16, 0, 0);   \
    } while (0)

    // Q fragments: B-operand of swapped QK: col=n (l15), k=c (g*8+j)
    f16x8 q[2][4];
#pragma unroll
    for (int ns = 0; ns < 2; ++ns)
#pragma unroll
        for (int cc = 0; cc < 4; ++cc)
            q[ns][cc] = *(const f16x8*)(xtb + (size_t)(nbase + ns * 16 + l15) * NC_ + cc * 32 + g * 8);

    f32x4 acc[8][2];
#pragma unroll
    for (int cs = 0; cs < 8; ++cs)
#pragma unroll
        for (int ns = 0; ns < 2; ++ns)
            acc[cs][ns] = (f32x4){0.f, 0.f, 0.f, 0.f};
    f32x4 accl[2];
    accl[0] = (f32x4){0.f, 0.f, 0.f, 0.f};
    accl[1] = (f32x4){0.f, 0.f, 0.f, 0.f};
    s16x8 ones;
#pragma unroll
    for (int j = 0; j < 8; ++j) ones[j] = (short)0x3F80;   // bf16 1.0

    const int nsteps = (MSPLIT == 3) ? (mh < 2 ? 43 : 42) : 128;
    const int tile0 = (MSPLIT == 3) ? (mh * 43) : 0;

    // drain q loads so the in-loop vmcnt counts only STAGE glls
    asm volatile("s_waitcnt vmcnt(0)" ::: "memory");
    // prologue: stage tiles 0 and 1
    STAGE(tile0, 0);
    STAGE(tile0 + 1, 16384);

    const uint32_t perm_sel = 0x07060302u;   // {hi.b3,hi.b2, lo.b3,lo.b2}

    int cb = 0;                  // current buffer index
    for (int it = 0; it < nsteps; ++it) {
        // STAGE(it) landed when <=4 glls outstanding (= STAGE(it+1));
        // final iter has nothing behind it -> full drain.
        if (it < nsteps - 1) {
            asm volatile("s_waitcnt vmcnt(4)" ::: "memory");
        } else {
            asm volatile("s_waitcnt vmcnt(0)" ::: "memory");
        }
        __builtin_amdgcn_s_barrier();   // raw barrier: no compiler drain
        if (it + 2 < nsteps) {
            int b2 = cb + 2; if (b2 >= 3) b2 -= 3;
            STAGE(tile0 + it + 2, b2 * 16384);
        }

        const _Float16* Kc = (const _Float16*)(KVB + cb * 16384);
        const uint16_t* Vc = (const uint16_t*)(KVB + cb * 16384 + 8192);

        union PU { s16x8 v; uint32_t u[4]; };
        PU pf[2];
#pragma unroll
        for (int ms = 0; ms < 2; ++ms) {
            f16x8 kf[4];
#pragma unroll
            for (int cc = 0; cc < 4; ++cc)
                kf[cc] = *(const f16x8*)(Kc + (ms * 4 + cc) * 512 + l * 8);

            // swapped QK: S^T[m][n], row m = ms*16+g*4+r, col n = l15.
            f32x4 s[2];
            s[0] = (f32x4){0.f, 0.f, 0.f, 0.f};
            s[1] = (f32x4){0.f, 0.f, 0.f, 0.f};
            __builtin_amdgcn_s_setprio(1);
#pragma unroll
            for (int cc = 0; cc < 4; ++cc)
#pragma unroll
                for (int ns = 0; ns < 2; ++ns)
                    s[ns] = __builtin_amdgcn_mfma_f32_16x16x32_f16(kf[cc], q[ns][cc], s[ns], 0, 0, 0);
            __builtin_amdgcn_s_setprio(0);
#pragma unroll
            for (int ns = 0; ns < 2; ++ns) {
                // p = exp(-(S+64)) = exp2(S*-log2e - 64*log2e): fma + exp only
                float p0 = __builtin_exp2f(__builtin_fmaf(s[ns][0], -1.44269504089f, -92.3324826169f));
                float p1 = __builtin_exp2f(__builtin_fmaf(s[ns][1], -1.44269504089f, -92.3324826169f));
                float p2 = __builtin_exp2f(__builtin_fmaf(s[ns][2], -1.44269504089f, -92.3324826169f));
                float p3 = __builtin_exp2f(__builtin_fmaf(s[ns][3], -1.44269504089f, -92.3324826169f));
                // trunc-pack bf16 pairs in 1 inst each (slot j = ms*4+r, dualmap)
                uint32_t d0, d1;
                asm("v_perm_b32 %0, %1, %2, %3" : "=v"(d0) : "v"(p1), "v"(p0), "s"(perm_sel));
                asm("v_perm_b32 %0, %1, %2, %3" : "=v"(d1) : "v"(p3), "v"(p2), "s"(perm_sel));
                pf[ns].u[ms * 2 + 0] = d0;
                pf[ns].u[ms * 2 + 1] = d1;
            }
        }

        // PV k=32: acc[c][n] += V[c][m] * P[m][n]; l[n] via ones-row MFMA
        __builtin_amdgcn_s_setprio(1);
#pragma unroll
        for (int cs = 0; cs < 8; ++cs) {
            s16x8 vf = *(const s16x8*)(Vc + cs * 512 + l * 8);
#pragma unroll
            for (int ns = 0; ns < 2; ++ns)
                acc[cs][ns] = __builtin_amdgcn_mfma_f32_16x16x32_bf16(vf, pf[ns].v, acc[cs][ns], 0, 0, 0);
        }
#pragma unroll
        for (int ns = 0; ns < 2; ++ns)
            accl[ns] = __builtin_amdgcn_mfma_f32_16x16x32_bf16(ones, pf[ns].v, accl[ns], 0, 0, 0);
        __builtin_amdgcn_s_setprio(0);

        ++cb; if (cb >= 3) cb = 0;
    }
#undef STAGE

    // accl rows are all identical = l[n=l15]: no cross-lane reduce needed
    float lred[2], linv[2];
#pragma unroll
    for (int ns = 0; ns < 2; ++ns) {
        lred[ns] = accl[ns][0];
        linv[ns] = 1.0f / lred[ns];
    }

    if (MSPLIT > 1) {
        // write self-normalized bf16 partial + fp32 l
        uint16_t* opb = Opart + (size_t)((b * 32 + nb) * MSPLIT + mh) * 16384;
#pragma unroll
        for (int cs = 0; cs < 8; ++cs)
#pragma unroll
            for (int ns = 0; ns < 2; ++ns)
#pragma unroll
                for (int r = 0; r < 4; ++r)
                    opb[(cs * 16 + g * 4 + r) * 128 + w * 32 + ns * 16 + l15] =
                        f2bf(acc[cs][ns][r] * linv[ns]);
        if (g == 0) {
            size_t lb = (size_t)((b * 32 + nb) * MSPLIT + mh) * 128;
#pragma unroll
            for (int ns = 0; ns < 2; ++ns)
                lpart[lb + w * 32 + ns * 16 + l15] = lred[ns];
        }
    } else {
        float gm = gamma[0];
        const float* ptsb = pts + (size_t)b * NC_ * NN_;
        float* outb = out + (size_t)b * NC_ * NN_;
#pragma unroll
        for (int cs = 0; cs < 8; ++cs)
#pragma unroll
            for (int ns = 0; ns < 2; ++ns)
#pragma unroll
                for (int r = 0; r < 4; ++r) {
                    size_t idx = (size_t)(cs * 16 + g * 4 + r) * NN_ + nbase + ns * 16 + l15;
                    outb[idx] = gm * acc[cs][ns][r] * linv[ns] + ptsb[idx];
                }
    }
}

// -------- epilogue: out = gamma * (sum o_i * l_i) / (sum l_i) + pts -------
template <int NS>
__global__ __launch_bounds__(256) void epi_kernel(
        const float* __restrict__ pts, const float* __restrict__ gamma,
        const uint16_t* __restrict__ Opart, const float* __restrict__ lpart,
        float* __restrict__ out) {
    size_t t = (size_t)blockIdx.x * 256 + threadIdx.x;
    size_t e = t * 4;
    int b = (int)(e >> 19);           // / (128*4096)
    int r = (int)(e & 524287);
    int c = r >> 12;
    int n = r & 4095;
    int nb = n >> 7, nl = n & 127;
    int base = (b * 32 + nb) * NS;
    f32x4 osum = (f32x4){0.f, 0.f, 0.f, 0.f};
    f32x4 lsum = (f32x4){0.f, 0.f, 0.f, 0.f};
#pragma unroll
    for (int i = 0; i < NS; ++i) {
        u16x4 o16 = *(const u16x4*)(Opart + (size_t)(base + i) * 16384 + c * 128 + nl);
        f32x4 li = *(const f32x4*)(lpart + (size_t)(base + i) * 128 + nl);
#pragma unroll
        for (int j = 0; j < 4; ++j) {
            osum[j] += bf2f(o16[j]) * li[j];
            lsum[j] += li[j];
        }
    }
    f32x4 p = *(const f32x4*)(pts + e);
    float gm = gamma[0];
    f32x4 res;
#pragma unroll
    for (int j = 0; j < 4; ++j)
        res[j] = gm * osum[j] / lsum[j] + p[j];
    *(f32x4*)(out + e) = res;
}

extern "C" void kernel_launch(void* const* d_in, const int* in_sizes, int n_in,
                              void* d_out, int out_size, void* d_ws, size_t ws_size,
                              hipStream_t stream) {
    const float* pts = (const float*)d_in[0];
    const float* gamma = (const float*)d_in[1];
    float* out = (float*)d_out;

    char* ws = (char*)d_ws;
    _Float16* xt = (_Float16*)ws;                              // 8 MB
    _Float16* Kf = (_Float16*)(ws + 8388608);                  // 8 MB
    uint16_t* Vf = (uint16_t*)(ws + 16777216);                 // 8 MB
    uint16_t* Opart = (uint16_t*)(ws + 25165824);              // 24 MB (bf16, msplit3)
    float* lpart = (float*)(ws + 25165824 + 25165824);         // 384 KB
    const size_t WS3 = 25165824ull + 25165824ull + 393216ull;  // 50.9 MB

    prep_kernel<<<1024, 256, 0, stream>>>(pts, xt, Kf, Vf);
    if (ws_size >= WS3) {
        flash_kernel<3><<<768, 256, 0, stream>>>(xt, Kf, Vf, Opart, lpart, pts, gamma, out);
        epi_kernel<3><<<4096, 256, 0, stream>>>(pts, gamma, Opart, lpart, out);
    } else {
        flash_kernel<1><<<256, 256, 0, stream>>>(xt, Kf, Vf, nullptr, nullptr, pts, gamma, out);
    }
}

// Round 21
// 90.623 us; speedup vs baseline: 1.1123x; 1.1123x over previous
//
#include <hip/hip_runtime.h>
#include <stdint.h>

#define NB_ 8
#define NC_ 128
#define NN_ 4096

typedef float f32x4 __attribute__((ext_vector_type(4)));
typedef _Float16 f16x8 __attribute__((ext_vector_type(8)));
typedef short s16x8 __attribute__((ext_vector_type(8)));
typedef unsigned short u16x4 __attribute__((ext_vector_type(4)));

__device__ __forceinline__ uint16_t f2bf(float f) {
    union { float f; uint32_t u; } v; v.f = f;
    return (uint16_t)((v.u + 0x7FFFu + ((v.u >> 16) & 1u)) >> 16);
}
__device__ __forceinline__ float bf2f(uint16_t b) {
    union { uint32_t u; float f; } v; v.u = ((uint32_t)b) << 16;
    return v.f;
}

// ---- prep: xt = fp16 x^T [N][C] (Q loads) + fragment-ordered Kf / Vf ----
// Kf chunk (tile t, ms, cc): lane l holds x^T[t*32+ms*16+(l&15)][cc*32+(l>>4)*8+j]
//   fp16 x8, at Kf[((t*8+ms*4+cc)*64+l)*8]  (k=32 QK A/B layout).
// Vf chunk (tile t, cs): lane l, slot j holds x[cs*16+(l&15)][t*32 + dualmap]
//   where dualmap(g,j) = (j<4) ? g*4+j : 16+g*4+(j-4)  -- matches the slot map
//   of the in-register P (both ms-halves) -> zero-shuffle k=32 PV.
__global__ __launch_bounds__(256) void prep_kernel(
        const float* __restrict__ pts, _Float16* __restrict__ xt,
        _Float16* __restrict__ Kf, uint16_t* __restrict__ Vf) {
    __shared__ float T[64][65];
    int bid = blockIdx.x;
    int ct = bid & 1, nt = (bid >> 1) & 63, b = bid >> 7;
    int c0 = ct * 64, n0 = nt * 64;
    int lr = threadIdx.x >> 6, lc = threadIdx.x & 63;
    const float* src = pts + ((size_t)b * NC_ + c0) * NN_ + n0;
#pragma unroll
    for (int r = 0; r < 16; ++r) {
        int cl = r * 4 + lr;
        T[cl][lc] = src[(size_t)cl * NN_ + lc];
    }
    __syncthreads();
#pragma unroll
    for (int r = 0; r < 16; ++r) {
        int nl = r * 4 + lr;
        xt[((size_t)b * NN_ + n0 + nl) * NC_ + c0 + lc] = (_Float16)T[lc][nl];
    }

    int w = threadIdx.x >> 6, l = threadIdx.x & 63, l15 = l & 15, g = l >> 4;
    _Float16* Kfb = Kf + (size_t)b * 524288;
    uint16_t* Vfb = Vf + (size_t)b * 524288;
#pragma unroll
    for (int e = 0; e < 2; ++e) {
        int q2 = w + e * 4;
        int tl = q2 >> 2, msq = (q2 >> 1) & 1, ccl = q2 & 1;
        int t = nt * 2 + tl, cc = ct * 2 + ccl;
        f16x8 kv;
#pragma unroll
        for (int j = 0; j < 8; ++j)
            kv[j] = (_Float16)T[ccl * 32 + g * 8 + j][tl * 32 + msq * 16 + l15];
        *(f16x8*)(Kfb + (((size_t)t * 8 + msq * 4 + cc) * 64 + l) * 8) = kv;
    }
#pragma unroll
    for (int e = 0; e < 2; ++e) {
        int q2 = w + e * 4;
        int tl = q2 >> 2, csl = q2 & 3;
        int t = nt * 2 + tl, cs = ct * 4 + csl;
        s16x8 vv;
#pragma unroll
        for (int j = 0; j < 8; ++j) {
            int m = (j < 4) ? (g * 4 + j) : (16 + g * 4 + (j - 4));
            vv[j] = (short)f2bf(T[csl * 16 + l15][tl * 32 + m]);
        }
        *(s16x8*)(Vfb + (((size_t)t * 8 + cs) * 64 + l) * 8) = vv;
    }
}

// ---------------- flash: fused QK^T -> exp -> PV, fixed shift 64 ----------
// R19 skeleton (T4 counted vmcnt(4), raw s_barrier, triple-buffered K/V,
// fragment-linear gll staging) + the two VERIFIED VALU cuts from R20:
//  - lsum via ones-row MFMA (accl): removes 16 adds/iter + end shuffles.
//  - bf16-trunc pack via v_perm_b32 (1 inst/pair, bit-exact verified).
// exp path = __expf (HIP fast intrinsic -> v_mul+v_exp; R20's exp2f libm
// path regressed VALU 44->55%). Zero-shuffle P (swapped QK + dualmap k=32
// PV). Partials self-normalized (bf16 O/l + fp32 l). (256,3): cap 170.
template <int MSPLIT>
__global__ __launch_bounds__(256, 3) void flash_kernel(
        const _Float16* __restrict__ xt, const _Float16* __restrict__ Kf,
        const uint16_t* __restrict__ Vf,
        uint16_t* __restrict__ Opart, float* __restrict__ lpart,
        const float* __restrict__ pts, const float* __restrict__ gamma,
        float* __restrict__ out) {
    int bid = blockIdx.x;
    int b = bid & 7;
    int rest = bid >> 3;
    int nb = rest & 31;
    int mh = rest >> 5;          // 0..MSPLIT-1
    int tid = threadIdx.x;
    int w = tid >> 6, l = tid & 63, l15 = l & 15, g = l >> 4;

    // 3 buffers x (8KB K + 8KB V), fragment-linear
    __shared__ __align__(16) uint16_t KV[3 * 8192];

    int nbase = nb * 128 + w * 32;
    const _Float16* xtb = xt + (size_t)b * NN_ * NC_;
    const char* KfB = (const char*)(Kf + (size_t)b * 524288);
    const char* VfB = (const char*)(Vf + (size_t)b * 524288);
    char* KVB = (char*)KV;
    int so = tid * 16;           // thread's 16B slot (linear staging)

    // 4 gll loads per STAGE (K 2 halves + V 2 halves)
#define STAGE(TILE, BUFOFF) do {                                                       \
        size_t gb_ = (size_t)(TILE) * 8192 + so;                                       \
        int lb_ = (BUFOFF) + so;                                                       \
        __builtin_amdgcn_global_load_lds(                                              \
            (const __attribute__((address_space(1))) void*)(KfB + gb_),                \
            (__attribute__((address_space(3))) void*)(KVB + lb_), 16, 0, 0);           \
        __builtin_amdgcn_global_load_lds(                                              \
            (const __attribute__((address_space(1))) void*)(KfB + gb_ + 4096),         \
            (__attribute__((address_space(3))) void*)(KVB + lb_ + 4096), 16, 0, 0);    \
        __builtin_amdgcn_global_load_lds(                                              \
            (const __attribute__((address_space(1))) void*)(VfB + gb_),                \
            (__attribute__((address_space(3))) void*)(KVB + lb_ + 8192), 16, 0, 0);    \
        __builtin_amdgcn_global_load_lds(                                              \
            (const __attribute__((address_space(1))) void*)(VfB + gb_ + 4096),         \
            (__attribute__((address_space(3))) void*)(KVB + lb_ + 12288), 16, 0, 0);   \
    } while (0)

    // Q fragments: B-operand of swapped QK: col=n (l15), k=c (g*8+j)
    f16x8 q[2][4];
#pragma unroll
    for (int ns = 0; ns < 2; ++ns)
#pragma unroll
        for (int cc = 0; cc < 4; ++cc)
            q[ns][cc] = *(const f16x8*)(xtb + (size_t)(nbase + ns * 16 + l15) * NC_ + cc * 32 + g * 8);

    f32x4 acc[8][2];
#pragma unroll
    for (int cs = 0; cs < 8; ++cs)
#pragma unroll
        for (int ns = 0; ns < 2; ++ns)
            acc[cs][ns] = (f32x4){0.f, 0.f, 0.f, 0.f};
    f32x4 accl[2];
    accl[0] = (f32x4){0.f, 0.f, 0.f, 0.f};
    accl[1] = (f32x4){0.f, 0.f, 0.f, 0.f};
    s16x8 ones;
#pragma unroll
    for (int j = 0; j < 8; ++j) ones[j] = (short)0x3F80;   // bf16 1.0

    const int nsteps = (MSPLIT == 3) ? (mh < 2 ? 43 : 42) : 128;
    const int tile0 = (MSPLIT == 3) ? (mh * 43) : 0;

    // drain q loads so the in-loop vmcnt counts only STAGE glls
    asm volatile("s_waitcnt vmcnt(0)" ::: "memory");
    // prologue: stage tiles 0 and 1
    STAGE(tile0, 0);
    STAGE(tile0 + 1, 16384);

    const uint32_t perm_sel = 0x07060302u;   // {hi.b3,hi.b2, lo.b3,lo.b2}

    int cb = 0;                  // current buffer index
    for (int it = 0; it < nsteps; ++it) {
        // STAGE(it) landed when <=4 glls outstanding (= STAGE(it+1));
        // final iter has nothing behind it -> full drain.
        if (it < nsteps - 1) {
            asm volatile("s_waitcnt vmcnt(4)" ::: "memory");
        } else {
            asm volatile("s_waitcnt vmcnt(0)" ::: "memory");
        }
        __builtin_amdgcn_s_barrier();   // raw barrier: no compiler drain
        if (it + 2 < nsteps) {
            int b2 = cb + 2; if (b2 >= 3) b2 -= 3;
            STAGE(tile0 + it + 2, b2 * 16384);
        }

        const _Float16* Kc = (const _Float16*)(KVB + cb * 16384);
        const uint16_t* Vc = (const uint16_t*)(KVB + cb * 16384 + 8192);

        union PU { s16x8 v; uint32_t u[4]; };
        PU pf[2];
#pragma unroll
        for (int ms = 0; ms < 2; ++ms) {
            f16x8 kf[4];
#pragma unroll
            for (int cc = 0; cc < 4; ++cc)
                kf[cc] = *(const f16x8*)(Kc + (ms * 4 + cc) * 512 + l * 8);

            // swapped QK: S^T[m][n], row m = ms*16+g*4+r, col n = l15.
            f32x4 s[2];
            s[0] = (f32x4){0.f, 0.f, 0.f, 0.f};
            s[1] = (f32x4){0.f, 0.f, 0.f, 0.f};
            __builtin_amdgcn_s_setprio(1);
#pragma unroll
            for (int cc = 0; cc < 4; ++cc)
#pragma unroll
                for (int ns = 0; ns < 2; ++ns)
                    s[ns] = __builtin_amdgcn_mfma_f32_16x16x32_f16(kf[cc], q[ns][cc], s[ns], 0, 0, 0);
            __builtin_amdgcn_s_setprio(0);
#pragma unroll
            for (int ns = 0; ns < 2; ++ns) {
                // P = exp(-(S+64)); __expf = HIP fast intrinsic (mul+v_exp)
                float p0 = __expf(-(s[ns][0] + 64.f));
                float p1 = __expf(-(s[ns][1] + 64.f));
                float p2 = __expf(-(s[ns][2] + 64.f));
                float p3 = __expf(-(s[ns][3] + 64.f));
                // trunc-pack bf16 pairs in 1 inst each (slot j = ms*4+r, dualmap)
                uint32_t d0, d1;
                asm("v_perm_b32 %0, %1, %2, %3" : "=v"(d0) : "v"(p1), "v"(p0), "s"(perm_sel));
                asm("v_perm_b32 %0, %1, %2, %3" : "=v"(d1) : "v"(p3), "v"(p2), "s"(perm_sel));
                pf[ns].u[ms * 2 + 0] = d0;
                pf[ns].u[ms * 2 + 1] = d1;
            }
        }

        // PV k=32: acc[c][n] += V[c][m] * P[m][n]; l[n] via ones-row MFMA
        __builtin_amdgcn_s_setprio(1);
#pragma unroll
        for (int cs = 0; cs < 8; ++cs) {
            s16x8 vf = *(const s16x8*)(Vc + cs * 512 + l * 8);
#pragma unroll
            for (int ns = 0; ns < 2; ++ns)
                acc[cs][ns] = __builtin_amdgcn_mfma_f32_16x16x32_bf16(vf, pf[ns].v, acc[cs][ns], 0, 0, 0);
        }
#pragma unroll
        for (int ns = 0; ns < 2; ++ns)
            accl[ns] = __builtin_amdgcn_mfma_f32_16x16x32_bf16(ones, pf[ns].v, accl[ns], 0, 0, 0);
        __builtin_amdgcn_s_setprio(0);

        ++cb; if (cb >= 3) cb = 0;
    }
#undef STAGE

    // accl rows are all identical = l[n=l15]: no cross-lane reduce needed
    float lred[2], linv[2];
#pragma unroll
    for (int ns = 0; ns < 2; ++ns) {
        lred[ns] = accl[ns][0];
        linv[ns] = 1.0f / lred[ns];
    }

    if (MSPLIT > 1) {
        // write self-normalized bf16 partial + fp32 l
        uint16_t* opb = Opart + (size_t)((b * 32 + nb) * MSPLIT + mh) * 16384;
#pragma unroll
        for (int cs = 0; cs < 8; ++cs)
#pragma unroll
            for (int ns = 0; ns < 2; ++ns)
#pragma unroll
                for (int r = 0; r < 4; ++r)
                    opb[(cs * 16 + g * 4 + r) * 128 + w * 32 + ns * 16 + l15] =
                        f2bf(acc[cs][ns][r] * linv[ns]);
        if (g == 0) {
            size_t lb = (size_t)((b * 32 + nb) * MSPLIT + mh) * 128;
#pragma unroll
            for (int ns = 0; ns < 2; ++ns)
                lpart[lb + w * 32 + ns * 16 + l15] = lred[ns];
        }
    } else {
        float gm = gamma[0];
        const float* ptsb = pts + (size_t)b * NC_ * NN_;
        float* outb = out + (size_t)b * NC_ * NN_;
#pragma unroll
        for (int cs = 0; cs < 8; ++cs)
#pragma unroll
            for (int ns = 0; ns < 2; ++ns)
#pragma unroll
                for (int r = 0; r < 4; ++r) {
                    size_t idx = (size_t)(cs * 16 + g * 4 + r) * NN_ + nbase + ns * 16 + l15;
                    outb[idx] = gm * acc[cs][ns][r] * linv[ns] + ptsb[idx];
                }
    }
}

// -------- epilogue: out = gamma * (sum o_i * l_i) / (sum l_i) + pts -------
template <int NS>
__global__ __launch_bounds__(256) void epi_kernel(
        const float* __restrict__ pts, const float* __restrict__ gamma,
        const uint16_t* __restrict__ Opart, const float* __restrict__ lpart,
        float* __restrict__ out) {
    size_t t = (size_t)blockIdx.x * 256 + threadIdx.x;
    size_t e = t * 4;
    int b = (int)(e >> 19);           // / (128*4096)
    int r = (int)(e & 524287);
    int c = r >> 12;
    int n = r & 4095;
    int nb = n >> 7, nl = n & 127;
    int base = (b * 32 + nb) * NS;
    f32x4 osum = (f32x4){0.f, 0.f, 0.f, 0.f};
    f32x4 lsum = (f32x4){0.f, 0.f, 0.f, 0.f};
#pragma unroll
    for (int i = 0; i < NS; ++i) {
        u16x4 o16 = *(const u16x4*)(Opart + (size_t)(base + i) * 16384 + c * 128 + nl);
        f32x4 li = *(const f32x4*)(lpart + (size_t)(base + i) * 128 + nl);
#pragma unroll
        for (int j = 0; j < 4; ++j) {
            osum[j] += bf2f(o16[j]) * li[j];
            lsum[j] += li[j];
        }
    }
    f32x4 p = *(const f32x4*)(pts + e);
    float gm = gamma[0];
    f32x4 res;
#pragma unroll
    for (int j = 0; j < 4; ++j)
        res[j] = gm * osum[j] / lsum[j] + p[j];
    *(f32x4*)(out + e) = res;
}

extern "C" void kernel_launch(void* const* d_in, const int* in_sizes, int n_in,
                              void* d_out, int out_size, void* d_ws, size_t ws_size,
                              hipStream_t stream) {
    const float* pts = (const float*)d_in[0];
    const float* gamma = (const float*)d_in[1];
    float* out = (float*)d_out;

    char* ws = (char*)d_ws;
    _Float16* xt = (_Float16*)ws;                              // 8 MB
    _Float16* Kf = (_Float16*)(ws + 8388608);                  // 8 MB
    uint16_t* Vf = (uint16_t*)(ws + 16777216);                 // 8 MB
    uint16_t* Opart = (uint16_t*)(ws + 25165824);              // 24 MB (bf16, msplit3)
    float* lpart = (float*)(ws + 25165824 + 25165824);         // 384 KB
    const size_t WS3 = 25165824ull + 25165824ull + 393216ull;  // 50.9 MB

    prep_kernel<<<1024, 256, 0, stream>>>(pts, xt, Kf, Vf);
    if (ws_size >= WS3) {
        flash_kernel<3><<<768, 256, 0, stream>>>(xt, Kf, Vf, Opart, lpart, pts, gamma, out);
        epi_kernel<3><<<4096, 256, 0, stream>>>(pts, gamma, Opart, lpart, out);
    } else {
        flash_kernel<1><<<256, 256, 0, stream>>>(xt, Kf, Vf, nullptr, nullptr, pts, gamma, out);
    }
}

// Round 22
// 89.188 us; speedup vs baseline: 1.1302x; 1.0161x over previous
//
#include <hip/hip_runtime.h>
#include <stdint.h>

#define NB_ 8
#define NC_ 128
#define NN_ 4096

typedef float f32x4 __attribute__((ext_vector_type(4)));
typedef _Float16 f16x8 __attribute__((ext_vector_type(8)));
typedef short s16x8 __attribute__((ext_vector_type(8)));
typedef unsigned short u16x4 __attribute__((ext_vector_type(4)));

__device__ __forceinline__ uint16_t f2bf(float f) {
    union { float f; uint32_t u; } v; v.f = f;
    return (uint16_t)((v.u + 0x7FFFu + ((v.u >> 16) & 1u)) >> 16);
}
__device__ __forceinline__ float bf2f(uint16_t b) {
    union { uint32_t u; float f; } v; v.u = ((uint32_t)b) << 16;
    return v.f;
}

// ---- prep: xt = fp16 x^T [N][C] (Q loads) + fragment-ordered Kf / Vf ----
// Kf chunk (tile t, ms, cc): lane l holds x^T[t*32+ms*16+(l&15)][cc*32+(l>>4)*8+j]
//   fp16 x8, at Kf[((t*8+ms*4+cc)*64+l)*8]  (k=32 QK A/B layout).
// Vf chunk (tile t, cs): lane l, slot j holds x[cs*16+(l&15)][t*32 + dualmap]
//   where dualmap(g,j) = (j<4) ? g*4+j : 16+g*4+(j-4)  -- matches the slot map
//   of the in-register P (both ms-halves) -> zero-shuffle k=32 PV.
__global__ __launch_bounds__(256) void prep_kernel(
        const float* __restrict__ pts, _Float16* __restrict__ xt,
        _Float16* __restrict__ Kf, uint16_t* __restrict__ Vf) {
    __shared__ float T[64][65];
    int bid = blockIdx.x;
    int ct = bid & 1, nt = (bid >> 1) & 63, b = bid >> 7;
    int c0 = ct * 64, n0 = nt * 64;
    int lr = threadIdx.x >> 6, lc = threadIdx.x & 63;
    const float* src = pts + ((size_t)b * NC_ + c0) * NN_ + n0;
#pragma unroll
    for (int r = 0; r < 16; ++r) {
        int cl = r * 4 + lr;
        T[cl][lc] = src[(size_t)cl * NN_ + lc];
    }
    __syncthreads();
#pragma unroll
    for (int r = 0; r < 16; ++r) {
        int nl = r * 4 + lr;
        xt[((size_t)b * NN_ + n0 + nl) * NC_ + c0 + lc] = (_Float16)T[lc][nl];
    }

    int w = threadIdx.x >> 6, l = threadIdx.x & 63, l15 = l & 15, g = l >> 4;
    _Float16* Kfb = Kf + (size_t)b * 524288;
    uint16_t* Vfb = Vf + (size_t)b * 524288;
#pragma unroll
    for (int e = 0; e < 2; ++e) {
        int q2 = w + e * 4;
        int tl = q2 >> 2, msq = (q2 >> 1) & 1, ccl = q2 & 1;
        int t = nt * 2 + tl, cc = ct * 2 + ccl;
        f16x8 kv;
#pragma unroll
        for (int j = 0; j < 8; ++j)
            kv[j] = (_Float16)T[ccl * 32 + g * 8 + j][tl * 32 + msq * 16 + l15];
        *(f16x8*)(Kfb + (((size_t)t * 8 + msq * 4 + cc) * 64 + l) * 8) = kv;
    }
#pragma unroll
    for (int e = 0; e < 2; ++e) {
        int q2 = w + e * 4;
        int tl = q2 >> 2, csl = q2 & 3;
        int t = nt * 2 + tl, cs = ct * 4 + csl;
        s16x8 vv;
#pragma unroll
        for (int j = 0; j < 8; ++j) {
            int m = (j < 4) ? (g * 4 + j) : (16 + g * 4 + (j - 4));
            vv[j] = (short)f2bf(T[csl * 16 + l15][tl * 32 + m]);
        }
        *(s16x8*)(Vfb + (((size_t)t * 8 + cs) * 64 + l) * 8) = vv;
    }
}

// ---------------- flash: fused QK^T -> exp -> PV, fixed shift 64 ----------
// R21 skeleton (T4 counted vmcnt(4), raw s_barrier, triple-buffered K/V,
// fragment-linear gll staging, ones-MFMA lsum, v_perm bf16 pack) with the
// exp path tightened to fma + raw v_exp_f32 (2 insts/value; 2^(s*-log2e
// - 64*log2e) = e^(-s-64); avoids both the 3-inst __expf sequence and
// R20's libm exp2f call). Zero-shuffle P (swapped QK + dualmap k=32 PV).
// Partials self-normalized (bf16 O/l + fp32 l). (256,3): cap 170.
template <int MSPLIT>
__global__ __launch_bounds__(256, 3) void flash_kernel(
        const _Float16* __restrict__ xt, const _Float16* __restrict__ Kf,
        const uint16_t* __restrict__ Vf,
        uint16_t* __restrict__ Opart, float* __restrict__ lpart,
        const float* __restrict__ pts, const float* __restrict__ gamma,
        float* __restrict__ out) {
    int bid = blockIdx.x;
    int b = bid & 7;
    int rest = bid >> 3;
    int nb = rest & 31;
    int mh = rest >> 5;          // 0..MSPLIT-1
    int tid = threadIdx.x;
    int w = tid >> 6, l = tid & 63, l15 = l & 15, g = l >> 4;

    // 3 buffers x (8KB K + 8KB V), fragment-linear
    __shared__ __align__(16) uint16_t KV[3 * 8192];

    int nbase = nb * 128 + w * 32;
    const _Float16* xtb = xt + (size_t)b * NN_ * NC_;
    const char* KfB = (const char*)(Kf + (size_t)b * 524288);
    const char* VfB = (const char*)(Vf + (size_t)b * 524288);
    char* KVB = (char*)KV;
    int so = tid * 16;           // thread's 16B slot (linear staging)

    // 4 gll loads per STAGE (K 2 halves + V 2 halves)
#define STAGE(TILE, BUFOFF) do {                                                       \
        size_t gb_ = (size_t)(TILE) * 8192 + so;                                       \
        int lb_ = (BUFOFF) + so;                                                       \
        __builtin_amdgcn_global_load_lds(                                              \
            (const __attribute__((address_space(1))) void*)(KfB + gb_),                \
            (__attribute__((address_space(3))) void*)(KVB + lb_), 16, 0, 0);           \
        __builtin_amdgcn_global_load_lds(                                              \
            (const __attribute__((address_space(1))) void*)(KfB + gb_ + 4096),         \
            (__attribute__((address_space(3))) void*)(KVB + lb_ + 4096), 16, 0, 0);    \
        __builtin_amdgcn_global_load_lds(                                              \
            (const __attribute__((address_space(1))) void*)(VfB + gb_),                \
            (__attribute__((address_space(3))) void*)(KVB + lb_ + 8192), 16, 0, 0);    \
        __builtin_amdgcn_global_load_lds(                                              \
            (const __attribute__((address_space(1))) void*)(VfB + gb_ + 4096),         \
            (__attribute__((address_space(3))) void*)(KVB + lb_ + 12288), 16, 0, 0);   \
    } while (0)

    // Q fragments: B-operand of swapped QK: col=n (l15), k=c (g*8+j)
    f16x8 q[2][4];
#pragma unroll
    for (int ns = 0; ns < 2; ++ns)
#pragma unroll
        for (int cc = 0; cc < 4; ++cc)
            q[ns][cc] = *(const f16x8*)(xtb + (size_t)(nbase + ns * 16 + l15) * NC_ + cc * 32 + g * 8);

    f32x4 acc[8][2];
#pragma unroll
    for (int cs = 0; cs < 8; ++cs)
#pragma unroll
        for (int ns = 0; ns < 2; ++ns)
            acc[cs][ns] = (f32x4){0.f, 0.f, 0.f, 0.f};
    f32x4 accl[2];
    accl[0] = (f32x4){0.f, 0.f, 0.f, 0.f};
    accl[1] = (f32x4){0.f, 0.f, 0.f, 0.f};
    s16x8 ones;
#pragma unroll
    for (int j = 0; j < 8; ++j) ones[j] = (short)0x3F80;   // bf16 1.0

    const int nsteps = (MSPLIT == 3) ? (mh < 2 ? 43 : 42) : 128;
    const int tile0 = (MSPLIT == 3) ? (mh * 43) : 0;

    // drain q loads so the in-loop vmcnt counts only STAGE glls
    asm volatile("s_waitcnt vmcnt(0)" ::: "memory");
    // prologue: stage tiles 0 and 1
    STAGE(tile0, 0);
    STAGE(tile0 + 1, 16384);

    const uint32_t perm_sel = 0x07060302u;   // {hi.b3,hi.b2, lo.b3,lo.b2}
    const float kLog2e = -1.44269504089f;    // -log2(e)
    const float kBias  = -92.3324826169f;    // -64*log2(e)

    int cb = 0;                  // current buffer index
    for (int it = 0; it < nsteps; ++it) {
        // STAGE(it) landed when <=4 glls outstanding (= STAGE(it+1));
        // final iter has nothing behind it -> full drain.
        if (it < nsteps - 1) {
            asm volatile("s_waitcnt vmcnt(4)" ::: "memory");
        } else {
            asm volatile("s_waitcnt vmcnt(0)" ::: "memory");
        }
        __builtin_amdgcn_s_barrier();   // raw barrier: no compiler drain
        if (it + 2 < nsteps) {
            int b2 = cb + 2; if (b2 >= 3) b2 -= 3;
            STAGE(tile0 + it + 2, b2 * 16384);
        }

        const _Float16* Kc = (const _Float16*)(KVB + cb * 16384);
        const uint16_t* Vc = (const uint16_t*)(KVB + cb * 16384 + 8192);

        union PU { s16x8 v; uint32_t u[4]; };
        PU pf[2];
#pragma unroll
        for (int ms = 0; ms < 2; ++ms) {
            f16x8 kf[4];
#pragma unroll
            for (int cc = 0; cc < 4; ++cc)
                kf[cc] = *(const f16x8*)(Kc + (ms * 4 + cc) * 512 + l * 8);

            // swapped QK: S^T[m][n], row m = ms*16+g*4+r, col n = l15.
            f32x4 s[2];
            s[0] = (f32x4){0.f, 0.f, 0.f, 0.f};
            s[1] = (f32x4){0.f, 0.f, 0.f, 0.f};
            __builtin_amdgcn_s_setprio(1);
#pragma unroll
            for (int cc = 0; cc < 4; ++cc)
#pragma unroll
                for (int ns = 0; ns < 2; ++ns)
                    s[ns] = __builtin_amdgcn_mfma_f32_16x16x32_f16(kf[cc], q[ns][cc], s[ns], 0, 0, 0);
            __builtin_amdgcn_s_setprio(0);
#pragma unroll
            for (int ns = 0; ns < 2; ++ns) {
                // P = e^(-S-64) = 2^(fma(S, -log2e, -64*log2e)): fma + v_exp only
                float x0 = __builtin_fmaf(s[ns][0], kLog2e, kBias);
                float x1 = __builtin_fmaf(s[ns][1], kLog2e, kBias);
                float x2 = __builtin_fmaf(s[ns][2], kLog2e, kBias);
                float x3 = __builtin_fmaf(s[ns][3], kLog2e, kBias);
                float p0, p1, p2, p3;
                asm("v_exp_f32 %0, %1" : "=v"(p0) : "v"(x0));
                asm("v_exp_f32 %0, %1" : "=v"(p1) : "v"(x1));
                asm("v_exp_f32 %0, %1" : "=v"(p2) : "v"(x2));
                asm("v_exp_f32 %0, %1" : "=v"(p3) : "v"(x3));
                // trunc-pack bf16 pairs in 1 inst each (slot j = ms*4+r, dualmap)
                uint32_t d0, d1;
                asm("v_perm_b32 %0, %1, %2, %3" : "=v"(d0) : "v"(p1), "v"(p0), "s"(perm_sel));
                asm("v_perm_b32 %0, %1, %2, %3" : "=v"(d1) : "v"(p3), "v"(p2), "s"(perm_sel));
                pf[ns].u[ms * 2 + 0] = d0;
                pf[ns].u[ms * 2 + 1] = d1;
            }
        }

        // PV k=32: acc[c][n] += V[c][m] * P[m][n]; l[n] via ones-row MFMA
        __builtin_amdgcn_s_setprio(1);
#pragma unroll
        for (int cs = 0; cs < 8; ++cs) {
            s16x8 vf = *(const s16x8*)(Vc + cs * 512 + l * 8);
#pragma unroll
            for (int ns = 0; ns < 2; ++ns)
                acc[cs][ns] = __builtin_amdgcn_mfma_f32_16x16x32_bf16(vf, pf[ns].v, acc[cs][ns], 0, 0, 0);
        }
#pragma unroll
        for (int ns = 0; ns < 2; ++ns)
            accl[ns] = __builtin_amdgcn_mfma_f32_16x16x32_bf16(ones, pf[ns].v, accl[ns], 0, 0, 0);
        __builtin_amdgcn_s_setprio(0);

        ++cb; if (cb >= 3) cb = 0;
    }
#undef STAGE

    // accl rows are all identical = l[n=l15]: no cross-lane reduce needed
    float lred[2], linv[2];
#pragma unroll
    for (int ns = 0; ns < 2; ++ns) {
        lred[ns] = accl[ns][0];
        linv[ns] = 1.0f / lred[ns];
    }

    if (MSPLIT > 1) {
        // write self-normalized bf16 partial + fp32 l
        uint16_t* opb = Opart + (size_t)((b * 32 + nb) * MSPLIT + mh) * 16384;
#pragma unroll
        for (int cs = 0; cs < 8; ++cs)
#pragma unroll
            for (int ns = 0; ns < 2; ++ns)
#pragma unroll
                for (int r = 0; r < 4; ++r)
                    opb[(cs * 16 + g * 4 + r) * 128 + w * 32 + ns * 16 + l15] =
                        f2bf(acc[cs][ns][r] * linv[ns]);
        if (g == 0) {
            size_t lb = (size_t)((b * 32 + nb) * MSPLIT + mh) * 128;
#pragma unroll
            for (int ns = 0; ns < 2; ++ns)
                lpart[lb + w * 32 + ns * 16 + l15] = lred[ns];
        }
    } else {
        float gm = gamma[0];
        const float* ptsb = pts + (size_t)b * NC_ * NN_;
        float* outb = out + (size_t)b * NC_ * NN_;
#pragma unroll
        for (int cs = 0; cs < 8; ++cs)
#pragma unroll
            for (int ns = 0; ns < 2; ++ns)
#pragma unroll
                for (int r = 0; r < 4; ++r) {
                    size_t idx = (size_t)(cs * 16 + g * 4 + r) * NN_ + nbase + ns * 16 + l15;
                    outb[idx] = gm * acc[cs][ns][r] * linv[ns] + ptsb[idx];
                }
    }
}

// -------- epilogue: out = gamma * (sum o_i * l_i) / (sum l_i) + pts -------
template <int NS>
__global__ __launch_bounds__(256) void epi_kernel(
        const float* __restrict__ pts, const float* __restrict__ gamma,
        const uint16_t* __restrict__ Opart, const float* __restrict__ lpart,
        float* __restrict__ out) {
    size_t t = (size_t)blockIdx.x * 256 + threadIdx.x;
    size_t e = t * 4;
    int b = (int)(e >> 19);           // / (128*4096)
    int r = (int)(e & 524287);
    int c = r >> 12;
    int n = r & 4095;
    int nb = n >> 7, nl = n & 127;
    int base = (b * 32 + nb) * NS;
    f32x4 osum = (f32x4){0.f, 0.f, 0.f, 0.f};
    f32x4 lsum = (f32x4){0.f, 0.f, 0.f, 0.f};
#pragma unroll
    for (int i = 0; i < NS; ++i) {
        u16x4 o16 = *(const u16x4*)(Opart + (size_t)(base + i) * 16384 + c * 128 + nl);
        f32x4 li = *(const f32x4*)(lpart + (size_t)(base + i) * 128 + nl);
#pragma unroll
        for (int j = 0; j < 4; ++j) {
            osum[j] += bf2f(o16[j]) * li[j];
            lsum[j] += li[j];
        }
    }
    f32x4 p = *(const f32x4*)(pts + e);
    float gm = gamma[0];
    f32x4 res;
#pragma unroll
    for (int j = 0; j < 4; ++j)
        res[j] = gm * osum[j] / lsum[j] + p[j];
    *(f32x4*)(out + e) = res;
}

extern "C" void kernel_launch(void* const* d_in, const int* in_sizes, int n_in,
                              void* d_out, int out_size, void* d_ws, size_t ws_size,
                              hipStream_t stream) {
    const float* pts = (const float*)d_in[0];
    const float* gamma = (const float*)d_in[1];
    float* out = (float*)d_out;

    char* ws = (char*)d_ws;
    _Float16* xt = (_Float16*)ws;                              // 8 MB
    _Float16* Kf = (_Float16*)(ws + 8388608);                  // 8 MB
    uint16_t* Vf = (uint16_t*)(ws + 16777216);                 // 8 MB
    uint16_t* Opart = (uint16_t*)(ws + 25165824);              // 24 MB (bf16, msplit3)
    float* lpart = (float*)(ws + 25165824 + 25165824);         // 384 KB
    const size_t WS3 = 25165824ull + 25165824ull + 393216ull;  // 50.9 MB

    prep_kernel<<<1024, 256, 0, stream>>>(pts, xt, Kf, Vf);
    if (ws_size >= WS3) {
        flash_kernel<3><<<768, 256, 0, stream>>>(xt, Kf, Vf, Opart, lpart, pts, gamma, out);
        epi_kernel<3><<<4096, 256, 0, stream>>>(pts, gamma, Opart, lpart, out);
    } else {
        flash_kernel<1><<<256, 256, 0, stream>>>(xt, Kf, Vf, nullptr, nullptr, pts, gamma, out);
    }
}